// Round 1
// baseline (440.543 us; speedup 1.0000x reference)
//
#include <hip/hip_runtime.h>
#include <cstdint>
#include <cstddef>

// Problem: out[m,n] = scale[m]*wscale[n]*(sum_k q[m,k]*w8[n,k] - azp[m]*azp_adj[n]) + bias[n]
//   M=8192 tokens, K=4096 in, N=4096 out. Exact int8 path => absmax driven only by
//   fp32 epilogue rounding (threshold 9.4, expect <0.1).

#define M_DIM 8192
#define K_DIM 4096
#define N_DIM 4096

typedef int v4i __attribute__((ext_vector_type(4)));

// ---------------------------------------------------------------------------
// Kernel 1: per-token asymmetric quantization. One 256-thread block per row.
// Bit-exactness notes: scale = (mx-mn)/255.0f (division, not *1/255);
// q = clip(rint(x/scale)+azp) with IEEE div + rint (half-to-even) == numpy.
// ---------------------------------------------------------------------------
__global__ __launch_bounds__(256) void quant_kernel(
    const float* __restrict__ x, signed char* __restrict__ q,
    float* __restrict__ scale_out, int* __restrict__ azp_out)
{
    const int m = blockIdx.x;
    const int t = threadIdx.x;
    const float4* row4 = (const float4*)(x + (size_t)m * K_DIM);

    float4 v[4];
    float mx = -3.4e38f, mn = 3.4e38f;
#pragma unroll
    for (int i = 0; i < 4; ++i) {
        v[i] = row4[t * 4 + i];
        mx = fmaxf(mx, fmaxf(fmaxf(v[i].x, v[i].y), fmaxf(v[i].z, v[i].w)));
        mn = fminf(mn, fminf(fminf(v[i].x, v[i].y), fminf(v[i].z, v[i].w)));
    }
    // wave64 reduce
#pragma unroll
    for (int off = 32; off; off >>= 1) {
        mx = fmaxf(mx, __shfl_down(mx, off));
        mn = fminf(mn, __shfl_down(mn, off));
    }
    __shared__ float smx[4], smn[4];
    if ((t & 63) == 0) { smx[t >> 6] = mx; smn[t >> 6] = mn; }
    __syncthreads();
    mx = fmaxf(fmaxf(smx[0], smx[1]), fmaxf(smx[2], smx[3]));
    mn = fminf(fminf(smn[0], smn[1]), fminf(smn[2], smn[3]));

    const float scale = (mx - mn) / 255.0f;           // match reference exactly
    const int azp = (int)rintf(-128.0f - mn / scale);
    if (t == 0) { scale_out[m] = scale; azp_out[m] = azp; }

    int packed[4];
    const float* vf = (const float*)v;
#pragma unroll
    for (int i = 0; i < 4; ++i) {
        int b[4];
#pragma unroll
        for (int j = 0; j < 4; ++j) {
            int qv = (int)rintf(vf[4 * i + j] / scale) + azp;
            qv = qv < -128 ? -128 : (qv > 127 ? 127 : qv);
            b[j] = qv;
        }
        packed[i] = (b[0] & 255) | ((b[1] & 255) << 8) | ((b[2] & 255) << 16) | ((b[3] & 255) << 24);
    }
    ((int4*)(q + (size_t)m * K_DIM))[t] = make_int4(packed[0], packed[1], packed[2], packed[3]);
}

// ---------------------------------------------------------------------------
// Kernel 2: weight prep. int32 [N,K] -> int8 [N,K] (values already in [-128,127])
// and azp_adj[n] = sum_k w[n,k]. One 256-thread block per n.
// ---------------------------------------------------------------------------
__global__ __launch_bounds__(256) void wprep_kernel(
    const int* __restrict__ w, signed char* __restrict__ w8, int* __restrict__ azp_adj)
{
    const int n = blockIdx.x;
    const int t = threadIdx.x;
    const int4* row = (const int4*)(w + (size_t)n * K_DIM);
    int sum = 0;
    int packed[4];
#pragma unroll
    for (int i = 0; i < 4; ++i) {
        int4 a = row[t * 4 + i];
        sum += a.x + a.y + a.z + a.w;
        packed[i] = (a.x & 255) | ((a.y & 255) << 8) | ((a.z & 255) << 16) | ((a.w & 255) << 24);
    }
    ((int4*)(w8 + (size_t)n * K_DIM))[t] = make_int4(packed[0], packed[1], packed[2], packed[3]);
#pragma unroll
    for (int off = 32; off; off >>= 1) sum += __shfl_down(sum, off);
    __shared__ int ssum[4];
    if ((t & 63) == 0) ssum[t >> 6] = sum;
    __syncthreads();
    if (t == 0) azp_adj[n] = ssum[0] + ssum[1] + ssum[2] + ssum[3];
}

// ---------------------------------------------------------------------------
// Kernel 3: int8 GEMM, m97 structure. 128x128 tile, BK=64, 4 waves, each wave
// a 64x64 subtile = 4x4 grid of mfma_i32_16x16x64_i8.
// A = q8 [M,K] row-major, B = w8 [N,K] row-major (so both frags read along K).
// Fragment maps (16x16x64 i8, by analogy with verified bf16 16x16x32):
//   A: m = lane&15, k = (lane>>4)*16 + j   (16 contiguous bytes -> ds_read_b128)
//   B: n = lane&15, k = (lane>>4)*16 + j
//   C/D: n = lane&15, m = (lane>>4)*4 + reg
// ---------------------------------------------------------------------------
__device__ __forceinline__ void async_copy16(const signed char* g, signed char* l) {
    __builtin_amdgcn_global_load_lds(
        (const __attribute__((address_space(1))) void*)g,
        (__attribute__((address_space(3))) void*)l, 16, 0, 0);
}

__global__ __launch_bounds__(256) void gemm_kernel(
    const signed char* __restrict__ A,   // [M,K]
    const signed char* __restrict__ B,   // [N,K]
    const float* __restrict__ scale, const int* __restrict__ azp,
    const int* __restrict__ azp_adj, const float* __restrict__ wscale,
    const float* __restrict__ bias, float* __restrict__ out)
{
    __shared__ signed char sA[128 * 64];  // 8 KB, [row][64] bytes
    __shared__ signed char sB[128 * 64];  // 8 KB

    const int t = threadIdx.x;
    const int wave = t >> 6;
    const int lane = t & 63;
    const int quad = lane >> 4;
    const int r16 = lane & 15;

    const int bm = blockIdx.y * 128;
    const int bn = blockIdx.x * 128;
    const int wm = (wave >> 1) * 64;   // wave's m offset in tile
    const int wn = (wave & 1) * 64;    // wave's n offset in tile

    v4i acc[4][4];
#pragma unroll
    for (int i = 0; i < 4; ++i)
#pragma unroll
        for (int j = 0; j < 4; ++j) acc[i][j] = (v4i){0, 0, 0, 0};

    // staging: thread t loads 16B at (row = t>>2, kbyte = (t&3)*16); two calls
    // cover 128 rows. LDS dst = t*16 => wave-uniform base + lane*16 (required).
    const int srow = t >> 2;
    const int scol = (t & 3) * 16;
    const signed char* ag0 = A + (size_t)(bm + srow) * K_DIM + scol;
    const signed char* ag1 = A + (size_t)(bm + 64 + srow) * K_DIM + scol;
    const signed char* bg0 = B + (size_t)(bn + srow) * K_DIM + scol;
    const signed char* bg1 = B + (size_t)(bn + 64 + srow) * K_DIM + scol;

    const v4i* sA4 = (const v4i*)sA;  // 16B granules: [row*4 + quad]
    const v4i* sB4 = (const v4i*)sB;

    for (int k0 = 0; k0 < K_DIM; k0 += 64) {
        async_copy16(ag0 + k0, sA + t * 16);
        async_copy16(ag1 + k0, sA + 4096 + t * 16);
        async_copy16(bg0 + k0, sB + t * 16);
        async_copy16(bg1 + k0, sB + 4096 + t * 16);
        __syncthreads();

        v4i af[4], bf[4];
#pragma unroll
        for (int i = 0; i < 4; ++i) {
            af[i] = sA4[(wm + i * 16 + r16) * 4 + quad];
            bf[i] = sB4[(wn + i * 16 + r16) * 4 + quad];
        }
#pragma unroll
        for (int i = 0; i < 4; ++i)
#pragma unroll
            for (int j = 0; j < 4; ++j)
                acc[i][j] = __builtin_amdgcn_mfma_i32_16x16x64_i8(af[i], bf[j], acc[i][j], 0, 0, 0);
        __syncthreads();
    }

    // epilogue: out = scale[m]*wscale[n]*(acc - azp[m]*adj[n]) + bias[n]
#pragma unroll
    for (int i = 0; i < 4; ++i) {
        const int mbase = bm + wm + i * 16 + quad * 4;
        float sm[4]; int am[4];
#pragma unroll
        for (int r = 0; r < 4; ++r) { sm[r] = scale[mbase + r]; am[r] = azp[mbase + r]; }
#pragma unroll
        for (int j = 0; j < 4; ++j) {
            const int n = bn + wn + j * 16 + r16;
            const float wsn = wscale[n];
            const int adjn = azp_adj[n];
            const float bn_ = bias[n];
#pragma unroll
            for (int r = 0; r < 4; ++r) {
                const int c = acc[i][j][r] - am[r] * adjn;
                out[(size_t)(mbase + r) * N_DIM + n] = sm[r] * wsn * (float)c + bn_;
            }
        }
    }
}

// ---------------------------------------------------------------------------
extern "C" void kernel_launch(void* const* d_in, const int* in_sizes, int n_in,
                              void* d_out, int out_size, void* d_ws, size_t ws_size,
                              hipStream_t stream) {
    const float* x      = (const float*)d_in[0];   // [M,K] fp32
    const int*   w      = (const int*)d_in[1];     // [N,K] int32 (int8 range)
    const float* wscale = (const float*)d_in[2];   // [N]
    const float* bias   = (const float*)d_in[3];   // [N]
    float* out = (float*)d_out;

    // workspace carve (all regions fully rewritten every launch; 0xAA poison ok)
    char* ws = (char*)d_ws;
    signed char* q8  = (signed char*)ws;                         // 32 MiB
    signed char* w8  = (signed char*)(ws + 33554432);            // 16 MiB
    float* scl       = (float*)(ws + 50331648);                  // 32 KiB
    int*   azp       = (int*)(ws + 50331648 + 32768);            // 32 KiB
    int*   adj       = (int*)(ws + 50331648 + 65536);            // 16 KiB

    quant_kernel<<<M_DIM, 256, 0, stream>>>(x, q8, scl, azp);
    wprep_kernel<<<N_DIM, 256, 0, stream>>>(w, w8, adj);
    dim3 grid(N_DIM / 128, M_DIM / 128);
    gemm_kernel<<<grid, 256, 0, stream>>>(q8, w8, scl, azp, adj, wscale, bias, out);
}

// Round 2
// 434.688 us; speedup vs baseline: 1.0135x; 1.0135x over previous
//
#include <hip/hip_runtime.h>
#include <cstdint>
#include <cstddef>

// out[m,n] = scale[m]*wscale[n]*(sum_k q[m,k]*w8[n,k] - azp[m]*azp_adj[n]) + bias[n]
// M=8192, K=4096, N=4096. Exact int8 path; absmax from fp32 epilogue only.

#define M_DIM 8192
#define K_DIM 4096
#define N_DIM 4096

typedef int v4i __attribute__((ext_vector_type(4)));

// ---------------------------------------------------------------------------
// Kernel 1: per-token asymmetric quantization. One 256-thread block per row.
// Lane-contiguous access: v[i] = row4[i*256 + t]  (16B/lane, 1KB/instr).
// Bit-exact: scale = (mx-mn)/255.0f, q = clip(rint(x/scale)+azp), rint = RNE.
// ---------------------------------------------------------------------------
__global__ __launch_bounds__(256) void quant_kernel(
    const float* __restrict__ x, signed char* __restrict__ q,
    float* __restrict__ scale_out, int* __restrict__ azp_out)
{
    const int m = blockIdx.x;
    const int t = threadIdx.x;
    const float4* row4 = (const float4*)(x + (size_t)m * K_DIM);

    float4 v[4];
    float mx = -3.4e38f, mn = 3.4e38f;
#pragma unroll
    for (int i = 0; i < 4; ++i) {
        v[i] = row4[i * 256 + t];                      // coalesced: lanes contiguous
        mx = fmaxf(mx, fmaxf(fmaxf(v[i].x, v[i].y), fmaxf(v[i].z, v[i].w)));
        mn = fminf(mn, fminf(fminf(v[i].x, v[i].y), fminf(v[i].z, v[i].w)));
    }
#pragma unroll
    for (int off = 32; off; off >>= 1) {
        mx = fmaxf(mx, __shfl_down(mx, off));
        mn = fminf(mn, __shfl_down(mn, off));
    }
    __shared__ float smx[4], smn[4];
    if ((t & 63) == 0) { smx[t >> 6] = mx; smn[t >> 6] = mn; }
    __syncthreads();
    mx = fmaxf(fmaxf(smx[0], smx[1]), fmaxf(smx[2], smx[3]));
    mn = fminf(fminf(smn[0], smn[1]), fminf(smn[2], smn[3]));

    const float scale = (mx - mn) / 255.0f;
    const int azp = (int)rintf(-128.0f - mn / scale);
    if (t == 0) { scale_out[m] = scale; azp_out[m] = azp; }

    int* qrow = (int*)(q + (size_t)m * K_DIM);
    const float* vf = (const float*)v;
#pragma unroll
    for (int i = 0; i < 4; ++i) {
        int b[4];
#pragma unroll
        for (int j = 0; j < 4; ++j) {
            int qv = (int)rintf(vf[4 * i + j] / scale) + azp;
            qv = qv < -128 ? -128 : (qv > 127 ? 127 : qv);
            b[j] = qv;
        }
        qrow[i * 256 + t] =
            (b[0] & 255) | ((b[1] & 255) << 8) | ((b[2] & 255) << 16) | ((b[3] & 255) << 24);
    }
}

// ---------------------------------------------------------------------------
// Kernel 2: weight prep, lane-contiguous. int32 [N,K] -> int8 [N,K] + col sums.
// ---------------------------------------------------------------------------
__global__ __launch_bounds__(256) void wprep_kernel(
    const int* __restrict__ w, signed char* __restrict__ w8, int* __restrict__ azp_adj)
{
    const int n = blockIdx.x;
    const int t = threadIdx.x;
    const int4* row = (const int4*)(w + (size_t)n * K_DIM);
    int* w8row = (int*)(w8 + (size_t)n * K_DIM);
    int sum = 0;
#pragma unroll
    for (int i = 0; i < 4; ++i) {
        int4 a = row[i * 256 + t];                     // coalesced
        sum += a.x + a.y + a.z + a.w;
        w8row[i * 256 + t] =
            (a.x & 255) | ((a.y & 255) << 8) | ((a.z & 255) << 16) | ((a.w & 255) << 24);
    }
#pragma unroll
    for (int off = 32; off; off >>= 1) sum += __shfl_down(sum, off);
    __shared__ int ssum[4];
    if ((t & 63) == 0) ssum[t >> 6] = sum;
    __syncthreads();
    if (t == 0) azp_adj[n] = ssum[0] + ssum[1] + ssum[2] + ssum[3];
}

// ---------------------------------------------------------------------------
// Kernel 3: int8 GEMM. 128x128 tile, BK=64, 4 waves x (4x4) mfma_i32_16x16x64_i8.
// LDS XOR swizzle: granule (row, colL) holds global (row, colL ^ ((row>>1)&3)).
//   - staging permutes the GLOBAL address per lane (LDS dst stays base+lane*16,
//     the mandatory global_load_lds layout)
//   - reads use granule = row*4 + (quad ^ ((row>>1)&3))
//   Bank check (16-lane phase, 256B): word = row*16 + col*4, bank depends on
//   (row&1, col); col = quad^((row>>1)&3) makes each (parity,col) pair appear
//   exactly twice over rows 0..15 -> 32 banks x 2 = free (m136: 2-way = 1.02x).
// ---------------------------------------------------------------------------
__device__ __forceinline__ void async_copy16(const signed char* g, signed char* l) {
    __builtin_amdgcn_global_load_lds(
        (const __attribute__((address_space(1))) void*)g,
        (__attribute__((address_space(3))) void*)l, 16, 0, 0);
}

__global__ __launch_bounds__(256) void gemm_kernel(
    const signed char* __restrict__ A,   // [M,K]
    const signed char* __restrict__ B,   // [N,K]
    const float* __restrict__ scale, const int* __restrict__ azp,
    const int* __restrict__ azp_adj, const float* __restrict__ wscale,
    const float* __restrict__ bias, float* __restrict__ out)
{
    __shared__ signed char sA[128 * 64];
    __shared__ signed char sB[128 * 64];

    const int t = threadIdx.x;
    const int wave = t >> 6;
    const int lane = t & 63;
    const int quad = lane >> 4;
    const int r16 = lane & 15;

    const int bm = blockIdx.y * 128;
    const int bn = blockIdx.x * 128;
    const int wm = (wave >> 1) * 64;
    const int wn = (wave & 1) * 64;

    v4i acc[4][4];
#pragma unroll
    for (int i = 0; i < 4; ++i)
#pragma unroll
        for (int j = 0; j < 4; ++j) acc[i][j] = (v4i){0, 0, 0, 0};

    // staging: thread t fills LDS granule t (row=t>>2, colL=t&3) with global
    // column colG = colL ^ ((row>>1)&3) = (t&3) ^ ((t>>3)&3). Row-periodic mod 8,
    // and 64 % 8 == 0, so the same expression serves the second 64-row half.
    const int srow = t >> 2;
    const int scol = ((t & 3) ^ ((t >> 3) & 3)) * 16;
    const signed char* ag0 = A + (size_t)(bm + srow) * K_DIM + scol;
    const signed char* ag1 = A + (size_t)(bm + 64 + srow) * K_DIM + scol;
    const signed char* bg0 = B + (size_t)(bn + srow) * K_DIM + scol;
    const signed char* bg1 = B + (size_t)(bn + 64 + srow) * K_DIM + scol;

    const v4i* sA4 = (const v4i*)sA;
    const v4i* sB4 = (const v4i*)sB;

    for (int k0 = 0; k0 < K_DIM; k0 += 64) {
        async_copy16(ag0 + k0, sA + t * 16);
        async_copy16(ag1 + k0, sA + 4096 + t * 16);
        async_copy16(bg0 + k0, sB + t * 16);
        async_copy16(bg1 + k0, sB + 4096 + t * 16);
        __syncthreads();

        v4i af[4], bf[4];
#pragma unroll
        for (int i = 0; i < 4; ++i) {
            const int ra = wm + i * 16 + r16;
            const int rb = wn + i * 16 + r16;
            af[i] = sA4[ra * 4 + (quad ^ ((ra >> 1) & 3))];
            bf[i] = sB4[rb * 4 + (quad ^ ((rb >> 1) & 3))];
        }
#pragma unroll
        for (int i = 0; i < 4; ++i)
#pragma unroll
            for (int j = 0; j < 4; ++j)
                acc[i][j] = __builtin_amdgcn_mfma_i32_16x16x64_i8(af[i], bf[j], acc[i][j], 0, 0, 0);
        __syncthreads();
    }

    // epilogue: out = scale[m]*wscale[n]*(acc - azp[m]*adj[n]) + bias[n]
#pragma unroll
    for (int i = 0; i < 4; ++i) {
        const int mbase = bm + wm + i * 16 + quad * 4;
        float sm[4]; int am[4];
#pragma unroll
        for (int r = 0; r < 4; ++r) { sm[r] = scale[mbase + r]; am[r] = azp[mbase + r]; }
#pragma unroll
        for (int j = 0; j < 4; ++j) {
            const int n = bn + wn + j * 16 + r16;
            const float wsn = wscale[n];
            const int adjn = azp_adj[n];
            const float bn_ = bias[n];
#pragma unroll
            for (int r = 0; r < 4; ++r) {
                const int c = acc[i][j][r] - am[r] * adjn;
                out[(size_t)(mbase + r) * N_DIM + n] = sm[r] * wsn * (float)c + bn_;
            }
        }
    }
}

// ---------------------------------------------------------------------------
extern "C" void kernel_launch(void* const* d_in, const int* in_sizes, int n_in,
                              void* d_out, int out_size, void* d_ws, size_t ws_size,
                              hipStream_t stream) {
    const float* x      = (const float*)d_in[0];
    const int*   w      = (const int*)d_in[1];
    const float* wscale = (const float*)d_in[2];
    const float* bias   = (const float*)d_in[3];
    float* out = (float*)d_out;

    char* ws = (char*)d_ws;
    signed char* q8  = (signed char*)ws;                         // 32 MiB
    signed char* w8  = (signed char*)(ws + 33554432);            // 16 MiB
    float* scl       = (float*)(ws + 50331648);                  // 32 KiB
    int*   azp       = (int*)(ws + 50331648 + 32768);            // 32 KiB
    int*   adj       = (int*)(ws + 50331648 + 65536);            // 16 KiB

    quant_kernel<<<M_DIM, 256, 0, stream>>>(x, q8, scl, azp);
    wprep_kernel<<<N_DIM, 256, 0, stream>>>(w, w8, adj);
    dim3 grid(N_DIM / 128, M_DIM / 128);
    gemm_kernel<<<grid, 256, 0, stream>>>(q8, w8, scl, azp, adj, wscale, bias, out);
}